// Round 9
// baseline (559.584 us; speedup 1.0000x reference)
//
#include <hip/hip_runtime.h>

#define T_LEN 8000
#define NTPB 125
#define NBLK 250
#define NLAYER 30
#define NLVL 6
#define GTILES 8
#define TILES_ALL (GTILES + NTPB)
#define SLAB ((size_t)TILES_ALL * 8192)   // shorts per slab (level,batch)
#define INV_SQRT2 0.70710678118f

typedef short bf16x8 __attribute__((ext_vector_type(8)));
typedef short s16x4  __attribute__((ext_vector_type(4)));
typedef unsigned uint2v __attribute__((ext_vector_type(2)));
typedef unsigned uint4v __attribute__((ext_vector_type(4)));
typedef float f32x4 __attribute__((ext_vector_type(4)));

// ---- LDS layout (shorts). slot = 512 shorts (64 rows x 8 ch) ----
#define R_HT  0            // h[t] 16 slots
#define R_OUT 8192         // gated out / y
#define R_CND 16384        // cond 12 slots
#define R_HD  22528        // h[t-d] window 16 slots
#define WBASE 30720        // 3 ring slots x 16384 shorts (32 KB each)
#define LDS_SHORTS 79872   // 156 KB

// ---- weight pack: per layer 26 klines (kline = 8 frags x 512 shorts) ----
#define LS 106496
#define C1 16384
#define C2 32768
#define C3 49152
#define C4 57344
#define C5 73728
#define C6 90112
#define IN_OFF   3194880
#define OUT1_OFF 3227648
#define OUT2_OFF 3244032

#define WAITV(N) asm volatile("s_waitcnt vmcnt(" #N ")" ::: "memory")
#define LGKM0    asm volatile("s_waitcnt lgkmcnt(0)" ::: "memory")
#define BAR      asm volatile("s_barrier" ::: "memory")

__device__ __forceinline__ unsigned short f2bf_u(float f) {
    union { float f; unsigned u; } v; v.f = f;
    unsigned u = v.u + 0x7FFFu + ((v.u >> 16) & 1u);
    return (unsigned short)(u >> 16);
}
__device__ __forceinline__ short f2bf(float f) { return (short)f2bf_u(f); }
__device__ __forceinline__ float bf2f(short s) {
    union { unsigned u; float f; } v; v.u = ((unsigned)(unsigned short)s) << 16;
    return v.f;
}
__device__ __forceinline__ unsigned cvtpk(float lo, float hi) {
    unsigned r;
    asm("v_cvt_pk_bf16_f32 %0, %1, %2" : "=v"(r) : "v"(lo), "v"(hi));
    return r;
}
__device__ __forceinline__ float gated_act(float av, float gv) {
    float e  = __expf(-2.f * fabsf(av));
    float th = (1.f - e) * __builtin_amdgcn_rcpf(1.f + e);
    th = (av < 0.f) ? -th : th;
    float sg = __builtin_amdgcn_rcpf(1.f + __expf(-gv));
    return th * sg;
}
__device__ __forceinline__ void ldg16_sc1(bf16x8* d, const short* p) {
    asm volatile("global_load_dwordx4 %0, %1, off sc1" : "=v"(*d) : "v"(p));
}
__device__ __forceinline__ void stg8_sc1(short* p, uint2v v) {
    asm volatile("global_store_dwordx2 %0, %1, off sc1" : : "v"(p), "v"(v) : "memory");
}
__device__ __forceinline__ void st_flag(int* p, int v) {
    __hip_atomic_store(p, v, __ATOMIC_RELAXED, __HIP_MEMORY_SCOPE_AGENT);
}
__device__ __forceinline__ void wait_ge(const int* p, int v) {
    while (__hip_atomic_load(p, __ATOMIC_RELAXED, __HIP_MEMORY_SCOPE_AGENT) < v)
        __builtin_amdgcn_s_sleep(1);
}
__device__ __forceinline__ f32x4 mfma_(bf16x8 a, bf16x8 b, f32x4 c) {
    return __builtin_amdgcn_mfma_f32_16x16x32_bf16(a, b, c, 0, 0, 0);
}
__device__ __forceinline__ void gload_lds16(const short* g, short* l) {
    __builtin_amdgcn_global_load_lds(
        (const __attribute__((address_space(1))) unsigned int*)g,
        (__attribute__((address_space(3))) unsigned int*)l, 16, 0, 0);
}
// 16-wave staging (input/head): 32 KB
__device__ __forceinline__ void stageW2(const short* src, short* dst, int wv, int lane) {
    gload_lds16(src + wv * 512 + lane * 8, dst + wv * 512);
    gload_lds16(src + (16 + wv) * 512 + lane * 8, dst + (16 + wv) * 512);
}
// 8-producer-wave staging: 32 KB (4 ops) / 16 KB (2 ops)
__device__ __forceinline__ void stageP4(const short* src, short* dst, int pv, int lane) {
#pragma unroll
    for (int r = 0; r < 4; ++r) {
        int o = (r * 8 + pv) * 64;
        gload_lds16(src + (o + lane) * 8, dst + o * 8);
    }
}
__device__ __forceinline__ void stageP2(const short* src, short* dst, int pv, int lane) {
#pragma unroll
    for (int r = 0; r < 2; ++r) {
        int o = (r * 8 + pv) * 64;
        gload_lds16(src + (o + lane) * 8, dst + o * 8);
    }
}

// consumer gemms: 2 tsubs, two A-streams sharing B
template<int NP>
__device__ __forceinline__ void pair2t(const short* wb, const short* sm, int reg,
                                       int tc0, int tc1, int ks0, int lg, int awoff,
                                       f32x4 (&A)[2][2], f32x4 (&G)[2][2])
{
#pragma unroll
    for (int p = 0; p < NP; ++p) {
        int slot = reg + ((ks0 + p) * 4 + lg) * 512;
        bf16x8 B0 = *(const bf16x8*)&sm[slot + tc0 * 8];
        bf16x8 B1 = *(const bf16x8*)&sm[slot + tc1 * 8];
#pragma unroll
        for (int mt = 0; mt < 2; ++mt) {
            bf16x8 a0 = *(const bf16x8*)&wb[p * 8192 + awoff + mt * 512];
            A[mt][0] = mfma_(a0, B0, A[mt][0]);
            A[mt][1] = mfma_(a0, B1, A[mt][1]);
            bf16x8 a1 = *(const bf16x8*)&wb[p * 8192 + 4096 + awoff + mt * 512];
            G[mt][0] = mfma_(a1, B0, G[mt][0]);
            G[mt][1] = mfma_(a1, B1, G[mt][1]);
        }
    }
}
__device__ __forceinline__ void d0gemm(const short* wb, const short* sm, int reg,
                                       int tc0, int tc1, int lg, int awoff,
                                       f32x4 (&A)[2][2])
{
#pragma unroll
    for (int ks = 0; ks < 4; ++ks) {
        int slot = reg + (ks * 4 + lg) * 512;
        bf16x8 B0 = *(const bf16x8*)&sm[slot + tc0 * 8];
        bf16x8 B1 = *(const bf16x8*)&sm[slot + tc1 * 8];
#pragma unroll
        for (int mt = 0; mt < 2; ++mt) {
            bf16x8 a = *(const bf16x8*)&wb[ks * 4096 + awoff + mt * 512];
            A[mt][0] = mfma_(a, B0, A[mt][0]);
            A[mt][1] = mfma_(a, B1, A[mt][1]);
        }
    }
}
// 16-wave single-stream (input/head)
template<int NP>
__device__ __forceinline__ void singleN(const short* wb, const short* sm, int boff,
                                        int ks0, int lg, int awoff, f32x4* ac)
{
#pragma unroll
    for (int p = 0; p < NP; ++p) {
        bf16x8 B = *(const bf16x8*)&sm[boff + ((ks0 + p) * 4 + lg) * 512];
#pragma unroll
        for (int mt = 0; mt < 2; ++mt) {
            bf16x8 a = *(const bf16x8*)&wb[p * 4096 + awoff + mt * 512];
            ac[mt] = mfma_(a, B, ac[mt]);
        }
    }
}

// ---------------- weight pack + flag/guard zero ----------------
__global__ __launch_bounds__(256) void k_pack(
    const float* __restrict__ dil_w, const float* __restrict__ gate_w,
    const float* __restrict__ cond_w, const float* __restrict__ condg_w,
    const float* __restrict__ res_w, const float* __restrict__ skip_w,
    const float* __restrict__ input_w, const float* __restrict__ out1_w,
    const float* __restrict__ out2_w,
    const float* __restrict__ dil_b, const float* __restrict__ cond_b,
    const float* __restrict__ gate_b, const float* __restrict__ condg_b,
    short* __restrict__ wp, short* __restrict__ hbt, int* __restrict__ flg)
{
    int gid = blockIdx.x * 256 + threadIdx.x;
    if (gid < 512) flg[gid] = 0;
    {
        int g2 = gid - 512;
        if (g2 >= 0 && g2 < 393216) {          // zero guard tiles of 12 slabs
            unsigned* hb32 = (unsigned*)hbt;
            int slab = g2 >> 15, off = g2 & 32767;
            hb32[(size_t)slab * (SLAB / 2) + off] = 0u;
        }
    }
    if (gid >= 6400 * 64) return;
    int fid = gid >> 6, lane = gid & 63;
    int lr = lane & 15, lg = lane >> 4;
    float v[8];
    if (fid < 6240) {
        int layer = fid / 208;
        int r = fid - layer * 208;
        int kl = r >> 3, f = r & 7;
        int m = f * 16 + lr;
        size_t mi = (size_t)layer * 128 + m;
        int mat, ks;
        if      (kl < 8)  { mat = (kl & 1) ? 2 : 1; ks = kl >> 1; }        // g : d1
        else if (kl < 14) { mat = (kl & 1) ? 4 : 3; ks = (kl - 8) >> 1; }  // cg : c
        else if (kl < 18) { mat = 0; ks = kl - 14; }                       // d0
        else              { mat = (kl & 1) ? 6 : 5; ks = (kl - 18) >> 1; } // s : r
        int kb = ks * 32 + lg * 8;
#pragma unroll
        for (int e = 0; e < 8; ++e) {
            int k = kb + e;
            float val;
            switch (mat) {
                case 0:  val = dil_w[(mi * 128 + k) * 2];     break;
                case 1:  val = dil_w[(mi * 128 + k) * 2 + 1]; break;
                case 2:  val = gate_w[mi * 128 + k]; break;
                case 3:  val = (k < 80) ? cond_w[mi * 80 + k]
                               : ((k == 80) ? dil_b[mi] + cond_b[mi] : 0.f); break;
                case 4:  val = (k < 80) ? condg_w[mi * 80 + k]
                               : ((k == 80) ? gate_b[mi] + condg_b[mi] : 0.f); break;
                case 5:  val = res_w[mi * 128 + k]; break;
                default: val = skip_w[mi * 128 + k]; break;
            }
            v[e] = val;
        }
    } else if (fid < 6304) {
        int f = fid - 6240; int ks = f >> 3, fr = f & 7;
        int m = fr * 16 + lr; int kb = ks * 32 + lg * 8;
#pragma unroll
        for (int e = 0; e < 8; ++e) v[e] = input_w[(size_t)m * 256 + kb + e];
    } else if (fid < 6336) {
        int f = fid - 6304; int ks = f >> 3, fr = f & 7;
        int m = fr * 16 + lr; int kb = ks * 32 + lg * 8;
#pragma unroll
        for (int e = 0; e < 8; ++e) v[e] = out1_w[(size_t)m * 128 + kb + e];
    } else {
        int f = fid - 6336; int mt = f & 15; int ks = f >> 4;
        int m = mt * 16 + lr; int kb = ks * 32 + lg * 8;
#pragma unroll
        for (int e = 0; e < 8; ++e) v[e] = out2_w[(size_t)m * 128 + kb + e];
    }
    short* dst = wp + (size_t)fid * 512 + lane * 8;
#pragma unroll
    for (int e = 0; e < 8; ++e) dst[e] = f2bf(v[e]);
}

// ---------------- persistent fused WaveNet (producer/consumer waves) ----------------
__global__ __launch_bounds__(1024, 4) void k_wavenet(
    const float* __restrict__ x, const float* __restrict__ cond,
    const short* __restrict__ wp, short* __restrict__ hbt,
    const float* __restrict__ ib, const float* __restrict__ rbias,
    const float* __restrict__ sbias, const float* __restrict__ b1,
    const float* __restrict__ b2, float* __restrict__ outp,
    int* __restrict__ rdy, int* __restrict__ dn)
{
    __shared__ __align__(16) short sm[LDS_SHORTS];

    const int tid  = threadIdx.x;
    const int lane = tid & 63;
    const int wv   = __builtin_amdgcn_readfirstlane(tid >> 6);   // 0..15
    const int wm   = wv & 3;
    const int wn4  = wv >> 2;
    const int lr   = lane & 15, lg = lane >> 4;
    const int bidx = blockIdx.x;
    const int b    = bidx / NTPB;
    const int ti   = bidx - b * NTPB;
    const int t0   = ti * 64;
    const int tl4  = wn4 * 16 + lr;
    const int tg4  = t0 + tl4;
    const int tl8  = tl4 * 8;
    const int lane8 = lane * 8;
    const int awoff = wm * 1024 + lane8;
    const int chA  = wm * 32 + lg * 4;
    const int kbA  = wm * 4 + (lg >> 1);
    const int e0   = (lg & 1) * 4;
    const bool cons = (wv < 8);
    const int pv   = wv - 8;
    const int wn2  = wn4 & 1;
    const int tc0  = wn2 * 32 + lr;
    const int tc1  = tc0 + 16;
    const int tgc0 = t0 + tc0;
    const int tgc1 = t0 + tc1;

    short* const sA = (short*)&sm[WBASE];
    short* const sB = (short*)&sm[WBASE + 16384];
    short* const sC = (short*)&sm[WBASE + 32768];

    // ---- stage input weights + x tile (slots 0..31) + cond ----
    stageW2(wp + IN_OFF, sA, wv, lane);
    stageW2(wp + IN_OFF + 16384, sB, wv, lane);
    {
        const float* xb = x + (size_t)b * 256 * T_LEN + t0 + lane;
#pragma unroll
        for (int it = 0; it < 2; ++it) {
            int kb = wv * 2 + it;
            unsigned pk[4];
#pragma unroll
            for (int e = 0; e < 4; ++e)
                pk[e] = cvtpk(xb[(size_t)(kb * 8 + 2 * e) * T_LEN],
                              xb[(size_t)(kb * 8 + 2 * e + 1) * T_LEN]);
            *(uint4v*)&sm[(kb * 64 + lane) * 8] = *(uint4v*)pk;
        }
        if (wv < 12) {
            const float* cb = cond + (size_t)b * 80 * T_LEN + t0 + lane;
            unsigned pk[4];
#pragma unroll
            for (int e = 0; e < 4; ++e) {
                int c0 = wv * 8 + 2 * e, c1 = c0 + 1;
                float v0 = (c0 < 80) ? cb[(size_t)c0 * T_LEN] : ((c0 == 80) ? 1.f : 0.f);
                float v1 = (c1 < 80) ? cb[(size_t)c1 * T_LEN] : 0.f;
                pk[e] = cvtpk(v0, v1);
            }
            *(uint4v*)&sm[R_CND + (wv * 64 + lane) * 8] = *(uint4v*)pk;
        }
    }
    __syncthreads();

    // ---- input conv (all 16 waves, 4x4 layout) ----
    {
        f32x4 acc[2] = {{0.f,0.f,0.f,0.f},{0.f,0.f,0.f,0.f}};
        singleN<4>(sA, sm, tl8, 0, lg, awoff, acc);
        singleN<4>(sB, sm, tl8, 4, lg, awoff, acc);
        __syncthreads();   // done reading x slots 0..15
        short* h0t = hbt + (size_t)(0 * 2 + b) * SLAB + (size_t)(ti + GTILES) * 8192;
#pragma unroll
        for (int mt = 0; mt < 2; ++mt) {
            int cb0 = chA + mt * 16;
            f32x4 hv = acc[mt] + (f32x4){ib[cb0], ib[cb0+1], ib[cb0+2], ib[cb0+3]};
            uint2v pk = {cvtpk(hv[0], hv[1]), cvtpk(hv[2], hv[3])};
            stg8_sc1(h0t + (kbA + mt * 2) * 512 + tl4 * 8 + e0, pk);
            *(uint2v*)&sm[R_HT + ((kbA + mt * 2) * 64 + tl4) * 8 + e0] = pk;
        }
    }
    WAITV(0); LGKM0;
    __syncthreads();
    if (tid == 0) st_flag(&rdy[bidx], 1);

    // consumer persistent state: re-read h0 (bf16) from R_HT
    f32x4 hres[2][2], skp[2][2];
    if (cons) {
#pragma unroll
        for (int mt = 0; mt < 2; ++mt) {
            s16x4 h0 = *(const s16x4*)&sm[R_HT + ((kbA + mt*2) * 64 + tc0) * 8 + e0];
            s16x4 h1 = *(const s16x4*)&sm[R_HT + ((kbA + mt*2) * 64 + tc1) * 8 + e0];
            hres[mt][0] = (f32x4){bf2f(h0[0]), bf2f(h0[1]), bf2f(h0[2]), bf2f(h0[3])};
            hres[mt][1] = (f32x4){bf2f(h1[0]), bf2f(h1[1]), bf2f(h1[2]), bf2f(h1[3])};
            skp[mt][0] = (f32x4){0.f,0.f,0.f,0.f};
            skp[mt][1] = (f32x4){0.f,0.f,0.f,0.f};
        }
    }

    // ---- 30 layers ----
    for (int li = 0; li < NLAYER; ++li) {
        const int d   = 1 << (li % 10);
        const int ksh = (d + 63) >> 6;
        const short* wl  = wp + (size_t)li * LS;
        const short* hcb = hbt + (size_t)((li % NLVL) * 2 + b) * SLAB;
        short*       hnb = hbt + (size_t)(((li + 1) % NLVL) * 2 + b) * SLAB;

        f32x4 rbv[2], sbv[2];
        if (cons) {
            const float* rbl = rbias + li * 128 + chA;
            const float* sbl = sbias + li * 128 + chA;
#pragma unroll
            for (int mt = 0; mt < 2; ++mt) {
                rbv[mt] = (f32x4){rbl[mt*16], rbl[mt*16+1], rbl[mt*16+2], rbl[mt*16+3]};
                sbv[mt] = (f32x4){sbl[mt*16], sbl[mt*16+1], sbl[mt*16+2], sbl[mt*16+3]};
            }
        } else {
            stageP4(wl,      sA, pv, lane);
            stageP4(wl + C1, sB, pv, lane);
            stageP4(wl + C2, sC, pv, lane);
            if (pv == 0 && lane == 0 && ti >= ksh)
                wait_ge(&rdy[bidx - ksh], li + 1);
            if (pv == 1 && lane == 0 && li >= NLVL - 1) {
                int d5 = 1 << ((li - (NLVL - 1)) % 10);
                int k5 = (d5 + 63) >> 6;
                if (ti + k5 < NTPB) wait_ge(&dn[bidx + k5], li - NLVL + 2);
            }
            WAITV(8);
        }
        BAR;                                   // BAR0: S0 ready, flags confirmed
        f32x4 aa[2][2], ag[2][2];
        if (cons) {
#pragma unroll
            for (int mt = 0; mt < 2; ++mt) {
                aa[mt][0] = (f32x4){0.f,0.f,0.f,0.f}; aa[mt][1] = (f32x4){0.f,0.f,0.f,0.f};
                ag[mt][0] = (f32x4){0.f,0.f,0.f,0.f}; ag[mt][1] = (f32x4){0.f,0.f,0.f,0.f};
            }
            pair2t<2>(sA, sm, R_HT, tc0, tc1, 0, lg, awoff, aa, ag);     // d1,g ks0-1
        } else {
            bf16x8 bh0, bh1;
            int kb0 = pv * 2;
            int gg = t0 - d + lane + GTILES * 64;
            const short* s0 = hcb + (size_t)(gg >> 6) * 8192 + kb0 * 512 + (gg & 63) * 8;
            ldg16_sc1(&bh0, s0);
            ldg16_sc1(&bh1, s0 + 512);
            WAITV(0);
            __builtin_amdgcn_sched_barrier(0);
            *(bf16x8*)&sm[R_HD + kb0 * 512 + lane8] = bh0;
            *(bf16x8*)&sm[R_HD + (kb0 + 1) * 512 + lane8] = bh1;
            LGKM0;
        }
        BAR;                                   // BAR1: S1 ready, R_HD staged
        if (cons) pair2t<2>(sB, sm, R_HT, tc0, tc1, 2, lg, awoff, aa, ag);  // d1,g ks2-3
        else      stageP2(wl + C3, sA, pv, lane);
        BAR;                                   // BAR2: S2 ready
        if (cons) pair2t<2>(sC, sm, R_CND, tc0, tc1, 0, lg, awoff, aa, ag); // c,cg ks0-1
        else    { stageP4(wl + C4, sB, pv, lane); WAITV(4); }
        BAR;                                   // BAR3: S3 ready
        if (cons) pair2t<1>(sA, sm, R_CND, tc0, tc1, 2, lg, awoff, aa, ag); // c,cg ks2
        else    { stageP4(wl + C5, sC, pv, lane); WAITV(4); }
        BAR;                                   // BAR4: S4 ready
        if (cons) {
            d0gemm(sB, sm, R_HD, tc0, tc1, lg, awoff, aa);                  // d0 @ h[t-d]
#pragma unroll
            for (int mt = 0; mt < 2; ++mt) {
                uint2v o0 = {cvtpk(gated_act(aa[mt][0][0], ag[mt][0][0]),
                                   gated_act(aa[mt][0][1], ag[mt][0][1])),
                             cvtpk(gated_act(aa[mt][0][2], ag[mt][0][2]),
                                   gated_act(aa[mt][0][3], ag[mt][0][3]))};
                uint2v o1 = {cvtpk(gated_act(aa[mt][1][0], ag[mt][1][0]),
                                   gated_act(aa[mt][1][1], ag[mt][1][1])),
                             cvtpk(gated_act(aa[mt][1][2], ag[mt][1][2]),
                                   gated_act(aa[mt][1][3], ag[mt][1][3]))};
                *(uint2v*)&sm[R_OUT + ((kbA + mt*2) * 64 + tc0) * 8 + e0] = o0;
                *(uint2v*)&sm[R_OUT + ((kbA + mt*2) * 64 + tc1) * 8 + e0] = o1;
            }
            LGKM0;
        } else { stageP4(wl + C6, sA, pv, lane); WAITV(4); }
        BAR;                                   // BAR5: S5 ready, R_OUT visible
        if (cons && wv == 0 && lane == 0) st_flag(&dn[bidx], li + 1);
        f32x4 ar[2][2], as2[2][2];
        if (cons) {
#pragma unroll
            for (int mt = 0; mt < 2; ++mt) {
                ar[mt][0] = (f32x4){0.f,0.f,0.f,0.f}; ar[mt][1] = (f32x4){0.f,0.f,0.f,0.f};
                as2[mt][0] = (f32x4){0.f,0.f,0.f,0.f}; as2[mt][1] = (f32x4){0.f,0.f,0.f,0.f};
            }
            pair2t<2>(sC, sm, R_OUT, tc0, tc1, 0, lg, awoff, ar, as2);      // r,s ks0-1
        } else {
            WAITV(0);
        }
        BAR;                                   // BAR6: S6 ready
        if (cons) {
            pair2t<2>(sA, sm, R_OUT, tc0, tc1, 2, lg, awoff, ar, as2);      // r,s ks2-3
#pragma unroll
            for (int mt = 0; mt < 2; ++mt) {
                hres[mt][0] = (hres[mt][0] + ar[mt][0] + rbv[mt]) * INV_SQRT2;
                hres[mt][1] = (hres[mt][1] + ar[mt][1] + rbv[mt]) * INV_SQRT2;
                skp[mt][0] = skp[mt][0] + as2[mt][0] + sbv[mt];
                skp[mt][1] = skp[mt][1] + as2[mt][1] + sbv[mt];
            }
            if (li < NLAYER - 1) {
                short* hti = hnb + (size_t)(ti + GTILES) * 8192;
#pragma unroll
                for (int mt = 0; mt < 2; ++mt) {
                    uint2v h0 = {cvtpk(hres[mt][0][0], hres[mt][0][1]),
                                 cvtpk(hres[mt][0][2], hres[mt][0][3])};
                    uint2v h1 = {cvtpk(hres[mt][1][0], hres[mt][1][1]),
                                 cvtpk(hres[mt][1][2], hres[mt][1][3])};
                    stg8_sc1(hti + (kbA + mt*2) * 512 + tc0 * 8 + e0, h0);
                    stg8_sc1(hti + (kbA + mt*2) * 512 + tc1 * 8 + e0, h1);
                    *(uint2v*)&sm[R_HT + ((kbA + mt*2) * 64 + tc0) * 8 + e0] = h0;
                    *(uint2v*)&sm[R_HT + ((kbA + mt*2) * 64 + tc1) * 8 + e0] = h1;
                }
            }
            WAITV(0); LGKM0;
        }
        BAR;                                   // BAR7: h stores drained, R_HT visible
        if (cons && wv == 0 && lane == 0 && li < NLAYER - 1)
            st_flag(&rdy[bidx], li + 2);
    }

    // ---- output head (all 16 waves, 4x4 layout) ----
    if (cons) {
#pragma unroll
        for (int mt = 0; mt < 2; ++mt) {
            uint2v s0 = {cvtpk(skp[mt][0][0], skp[mt][0][1]), cvtpk(skp[mt][0][2], skp[mt][0][3])};
            uint2v s1 = {cvtpk(skp[mt][1][0], skp[mt][1][1]), cvtpk(skp[mt][1][2], skp[mt][1][3])};
            *(uint2v*)&sm[R_HT + ((kbA + mt*2) * 64 + tc0) * 8 + e0] = s0;
            *(uint2v*)&sm[R_HT + ((kbA + mt*2) * 64 + tc1) * 8 + e0] = s1;
        }
    }
    stageW2(wp + OUT1_OFF, sA, wv, lane);
    stageW2(wp + OUT2_OFF, sB, wv, lane);
    stageW2(wp + OUT2_OFF + 16384, sC, wv, lane);
    __syncthreads();
    f32x4 ay[2] = {{0.f,0.f,0.f,0.f},{0.f,0.f,0.f,0.f}};
    singleN<4>(sA, sm, R_HT + tl8, 0, lg, awoff, ay);
#pragma unroll
    for (int mt = 0; mt < 2; ++mt) {
        int cb0 = chA + mt * 16;
        float y0 = fmaxf(ay[mt][0] + b1[cb0],     0.f);
        float y1 = fmaxf(ay[mt][1] + b1[cb0 + 1], 0.f);
        float y2 = fmaxf(ay[mt][2] + b1[cb0 + 2], 0.f);
        float y3 = fmaxf(ay[mt][3] + b1[cb0 + 3], 0.f);
        uint2v yv = {cvtpk(y0, y1), cvtpk(y2, y3)};
        *(uint2v*)&sm[R_OUT + ((kbA + mt * 2) * 64 + tl4) * 8 + e0] = yv;
    }
    __syncthreads();
    f32x4 ao[4] = {{0.f,0.f,0.f,0.f},{0.f,0.f,0.f,0.f},
                   {0.f,0.f,0.f,0.f},{0.f,0.f,0.f,0.f}};
    {
#pragma unroll
        for (int ksp = 0; ksp < 2; ++ksp) {
            bf16x8 B = *(const bf16x8*)&sm[R_OUT + tl8 + (ksp * 4 + lg) * 512];
#pragma unroll
            for (int mt = 0; mt < 4; ++mt) {
                int fg = 4 * wm + mt;
                bf16x8 A = *(const bf16x8*)&sB[(ksp * 2 + (fg >> 3)) * 4096 + (fg & 7) * 512 + lane8];
                ao[mt] = mfma_(A, B, ao[mt]);
            }
        }
#pragma unroll
        for (int ksp = 0; ksp < 2; ++ksp) {
            bf16x8 B = *(const bf16x8*)&sm[R_OUT + tl8 + ((2 + ksp) * 4 + lg) * 512];
#pragma unroll
            for (int mt = 0; mt < 4; ++mt) {
                int fg = 4 * wm + mt;
                bf16x8 A = *(const bf16x8*)&sC[(ksp * 2 + (fg >> 3)) * 4096 + (fg & 7) * 512 + lane8];
                ao[mt] = mfma_(A, B, ao[mt]);
            }
        }
    }
#pragma unroll
    for (int mt = 0; mt < 4; ++mt) {
        int ch2 = wm * 64 + mt * 16 + lg * 4;
        float* op = outp + ((size_t)(b * 256 + ch2)) * T_LEN + tg4;
        op[0]         = ao[mt][0] + b2[ch2];
        op[T_LEN]     = ao[mt][1] + b2[ch2 + 1];
        op[2 * T_LEN] = ao[mt][2] + b2[ch2 + 2];
        op[3 * T_LEN] = ao[mt][3] + b2[ch2 + 3];
    }
}

extern "C" void kernel_launch(void* const* d_in, const int* in_sizes, int n_in,
                              void* d_out, int out_size, void* d_ws, size_t ws_size,
                              hipStream_t stream)
{
    const float* x       = (const float*)d_in[0];
    const float* cond    = (const float*)d_in[1];
    const float* input_w = (const float*)d_in[2];
    const float* input_b = (const float*)d_in[3];
    const float* dil_w   = (const float*)d_in[4];
    const float* dil_b   = (const float*)d_in[5];
    const float* gate_w  = (const float*)d_in[6];
    const float* gate_b  = (const float*)d_in[7];
    const float* cond_w  = (const float*)d_in[8];
    const float* cond_b  = (const float*)d_in[9];
    const float* condg_w = (const float*)d_in[10];
    const float* condg_b = (const float*)d_in[11];
    const float* res_w   = (const float*)d_in[12];
    const float* res_b   = (const float*)d_in[13];
    const float* skip_w  = (const float*)d_in[14];
    const float* skip_b  = (const float*)d_in[15];
    const float* out1_w  = (const float*)d_in[16];
    const float* out1_b  = (const float*)d_in[17];
    const float* out2_w  = (const float*)d_in[18];
    const float* out2_b  = (const float*)d_in[19];
    float* outp = (float*)d_out;

    short* wpk = (short*)d_ws;                          // 6400*512 shorts
    short* hbt = wpk + (size_t)6400 * 512;              // 12 slabs (6 levels x 2 batches)
    int*   flg = (int*)(hbt + (size_t)12 * SLAB);
    int*   rdy = flg;
    int*   dn  = flg + 256;

    k_pack<<<1600, 256, 0, stream>>>(dil_w, gate_w, cond_w, condg_w, res_w, skip_w,
                                     input_w, out1_w, out2_w,
                                     dil_b, cond_b, gate_b, condg_b, wpk, hbt, flg);

    void* args[] = {(void*)&x, (void*)&cond, (void*)&wpk, (void*)&hbt,
                    (void*)&input_b, (void*)&res_b, (void*)&skip_b,
                    (void*)&out1_b, (void*)&out2_b, (void*)&outp,
                    (void*)&rdy, (void*)&dn};
    (void)hipLaunchCooperativeKernel((void*)k_wavenet, dim3(NBLK), dim3(1024), args, 0, stream);
}

// Round 11
// 302.462 us; speedup vs baseline: 1.8501x; 1.8501x over previous
//
#include <hip/hip_runtime.h>

#define T_LEN 8000
#define NTPB 125
#define NBLK 250
#define NLAYER 30
#define GUARD 512
#define HROWS (GUARD + T_LEN)
#define SLAB (HROWS * 128)          // shorts per h slab (level,batch)
#define INV_SQRT2 0.70710678118f

typedef short bf16x8 __attribute__((ext_vector_type(8)));
typedef unsigned uint2v __attribute__((ext_vector_type(2)));
typedef unsigned uint4v __attribute__((ext_vector_type(4)));
typedef float f32x4 __attribute__((ext_vector_type(4)));

// ---- LDS layout (shorts). slot = 512 shorts (64 rows x 8 ch) ----
#define R_HT  0          // h[t] 16 slots; x tile spans slots 0..31
#define R_OUT 8192       // gated out / y
#define R_CND 16384      // cond (12 slots; k=80 -> 1.0 bias col)
#define WBASE 22528      // 2 weight ring slots x 16384 shorts (32 KB each)
#define LDS_SHORTS 55296 // 108 KB

// ---- weight pack: per layer 26 klines (kline = 8 frags x 512 shorts) ----
#define LS 106496
#define C1 16384
#define C2 32768
#define C3 49152
#define C4 57344
#define C5 73728
#define C6 90112
#define IN_OFF   3194880
#define OUT1_OFF 3227648
#define OUT2_OFF 3244032

__device__ __forceinline__ unsigned short f2bf_u(float f) {
    union { float f; unsigned u; } v; v.f = f;
    unsigned u = v.u + 0x7FFFu + ((v.u >> 16) & 1u);
    return (unsigned short)(u >> 16);
}
__device__ __forceinline__ short f2bf(float f) { return (short)f2bf_u(f); }

__device__ __forceinline__ unsigned cvtpk(float lo, float hi) {
    unsigned r;
    asm("v_cvt_pk_bf16_f32 %0, %1, %2" : "=v"(r) : "v"(lo), "v"(hi));
    return r;
}
__device__ __forceinline__ float gated_act(float av, float gv) {
    float e  = __expf(-2.f * fabsf(av));
    float th = (1.f - e) * __builtin_amdgcn_rcpf(1.f + e);
    th = (av < 0.f) ? -th : th;
    float sg = __builtin_amdgcn_rcpf(1.f + __expf(-gv));
    return th * sg;
}
__device__ __forceinline__ void ldg16_sc1(bf16x8* d, const short* p) {
    asm volatile("global_load_dwordx4 %0, %1, off sc1" : "=v"(*d) : "v"(p));
}
__device__ __forceinline__ void stg8_sc1(short* p, uint2v v) {
    asm volatile("global_store_dwordx2 %0, %1, off sc1" : : "v"(p), "v"(v) : "memory");
}
__device__ __forceinline__ void st_flag(int* p, int v) {
    __hip_atomic_store(p, v, __ATOMIC_RELAXED, __HIP_MEMORY_SCOPE_AGENT);
}
__device__ __forceinline__ void wait_ge(const int* p, int v) {
    while (__hip_atomic_load(p, __ATOMIC_RELAXED, __HIP_MEMORY_SCOPE_AGENT) < v)
        __builtin_amdgcn_s_sleep(1);
}
__device__ __forceinline__ f32x4 mfma_(bf16x8 a, bf16x8 b, f32x4 c) {
    return __builtin_amdgcn_mfma_f32_16x16x32_bf16(a, b, c, 0, 0, 0);
}
__device__ __forceinline__ void gload_lds16(const short* g, short* l) {
    __builtin_amdgcn_global_load_lds(
        (const __attribute__((address_space(1))) unsigned int*)g,
        (__attribute__((address_space(3))) unsigned int*)l, 16, 0, 0);
}
// 8-wave staging: 32 KB chunk (4 issues/lane) / 16 KB (2 issues)
__device__ __forceinline__ void stage32(const short* src, short* dst, int wv, int lane) {
#pragma unroll
    for (int r = 0; r < 4; ++r) {
        int s = (r * 8 + wv) * 512;
        gload_lds16(src + s + lane * 8, dst + s);
    }
}
__device__ __forceinline__ void stage16(const short* src, short* dst, int wv, int lane) {
#pragma unroll
    for (int r = 0; r < 2; ++r) {
        int s = (r * 8 + wv) * 512;
        gload_lds16(src + s + lane * 8, dst + s);
    }
}

// two A-streams (pair-interleaved chunk), T=2: B0/B1 shared by both streams
template<int NP>
__device__ __forceinline__ void pairT2(const short* wb, const short* smp, int reg,
                                       int ks0, int tc0, int tc1, int lg, int awoff,
                                       f32x4 (&A)[2][2], f32x4 (&G)[2][2])
{
#pragma unroll
    for (int p = 0; p < NP; ++p) {
        int slot = reg + ((ks0 + p) * 4 + lg) * 512;
        bf16x8 B0 = *(const bf16x8*)&smp[slot + tc0 * 8];
        bf16x8 B1 = *(const bf16x8*)&smp[slot + tc1 * 8];
#pragma unroll
        for (int mt = 0; mt < 2; ++mt) {
            bf16x8 a0 = *(const bf16x8*)&wb[p * 8192 + awoff + mt * 512];
            A[mt][0] = mfma_(a0, B0, A[mt][0]);
            A[mt][1] = mfma_(a0, B1, A[mt][1]);
            bf16x8 a1 = *(const bf16x8*)&wb[p * 8192 + 4096 + awoff + mt * 512];
            G[mt][0] = mfma_(a1, B0, G[mt][0]);
            G[mt][1] = mfma_(a1, B1, G[mt][1]);
        }
    }
}
// single A-stream chunk ([ks][8frag] consecutive), T=2
template<int NP>
__device__ __forceinline__ void singleT2(const short* wb, const short* smp, int reg,
                                         int ks0, int tc0, int tc1, int lg, int awoff,
                                         f32x4 (&ac)[2][2])
{
#pragma unroll
    for (int p = 0; p < NP; ++p) {
        int slot = reg + ((ks0 + p) * 4 + lg) * 512;
        bf16x8 B0 = *(const bf16x8*)&smp[slot + tc0 * 8];
        bf16x8 B1 = *(const bf16x8*)&smp[slot + tc1 * 8];
#pragma unroll
        for (int mt = 0; mt < 2; ++mt) {
            bf16x8 a = *(const bf16x8*)&wb[p * 4096 + awoff + mt * 512];
            ac[mt][0] = mfma_(a, B0, ac[mt][0]);
            ac[mt][1] = mfma_(a, B1, ac[mt][1]);
        }
    }
}

// ---------------- weight pack + flag/guard zero ----------------
__global__ __launch_bounds__(256) void k_pack(
    const float* __restrict__ dil_w, const float* __restrict__ gate_w,
    const float* __restrict__ cond_w, const float* __restrict__ condg_w,
    const float* __restrict__ res_w, const float* __restrict__ skip_w,
    const float* __restrict__ input_w, const float* __restrict__ out1_w,
    const float* __restrict__ out2_w,
    const float* __restrict__ dil_b, const float* __restrict__ cond_b,
    const float* __restrict__ gate_b, const float* __restrict__ condg_b,
    short* __restrict__ wp, short* __restrict__ hbt, int* __restrict__ flg)
{
    int gid = blockIdx.x * 256 + threadIdx.x;
    if (gid < 512) flg[gid] = 0;
    {
        int g2 = gid - 512;
        if (g2 >= 0 && g2 < 262144) {      // zero guard rows of 8 slabs
            unsigned* hb32 = (unsigned*)hbt;
            int slab = g2 >> 15, off = g2 & 32767;
            hb32[(size_t)slab * (SLAB / 2) + off] = 0u;
        }
    }
    if (gid >= 6400 * 64) return;
    int fid = gid >> 6, lane = gid & 63;
    int lr = lane & 15, lg = lane >> 4;
    float v[8];
    if (fid < 6240) {
        int layer = fid / 208;
        int r = fid - layer * 208;
        int kl = r >> 3, f = r & 7;
        int m = f * 16 + lr;
        size_t mi = (size_t)layer * 128 + m;
        int mat, ks;
        if      (kl < 8)  { mat = (kl & 1) ? 2 : 1; ks = kl >> 1; }
        else if (kl < 14) { mat = (kl & 1) ? 4 : 3; ks = (kl - 8) >> 1; }
        else if (kl < 18) { mat = 0; ks = kl - 14; }
        else              { mat = (kl & 1) ? 6 : 5; ks = (kl - 18) >> 1; }
        int kb = ks * 32 + lg * 8;
#pragma unroll
        for (int e = 0; e < 8; ++e) {
            int k = kb + e;
            float val;
            switch (mat) {
                case 0:  val = dil_w[(mi * 128 + k) * 2];     break;
                case 1:  val = dil_w[(mi * 128 + k) * 2 + 1]; break;
                case 2:  val = gate_w[mi * 128 + k]; break;
                case 3:  val = (k < 80) ? cond_w[mi * 80 + k]
                               : ((k == 80) ? dil_b[mi] + cond_b[mi] : 0.f); break;
                case 4:  val = (k < 80) ? condg_w[mi * 80 + k]
                               : ((k == 80) ? gate_b[mi] + condg_b[mi] : 0.f); break;
                case 5:  val = res_w[mi * 128 + k]; break;
                default: val = skip_w[mi * 128 + k]; break;
            }
            v[e] = val;
        }
    } else if (fid < 6304) {
        int f = fid - 6240; int ks = f >> 3, fr = f & 7;
        int m = fr * 16 + lr; int kb = ks * 32 + lg * 8;
#pragma unroll
        for (int e = 0; e < 8; ++e) v[e] = input_w[(size_t)m * 256 + kb + e];
    } else if (fid < 6336) {
        int f = fid - 6304; int ks = f >> 3, fr = f & 7;
        int m = fr * 16 + lr; int kb = ks * 32 + lg * 8;
#pragma unroll
        for (int e = 0; e < 8; ++e) v[e] = out1_w[(size_t)m * 128 + kb + e];
    } else {
        int f = fid - 6336; int mt = f & 15; int ks = f >> 4;
        int m = mt * 16 + lr; int kb = ks * 32 + lg * 8;
#pragma unroll
        for (int e = 0; e < 8; ++e) v[e] = out2_w[(size_t)m * 128 + kb + e];
    }
    short* dst = wp + (size_t)fid * 512 + lane * 8;
#pragma unroll
    for (int e = 0; e < 8; ++e) dst[e] = f2bf(v[e]);
}

// ---------------- persistent fused WaveNet: 8 waves, C=2 T=2 ----------------
__global__ __launch_bounds__(512, 2) void k_wavenet(
    const float* __restrict__ x, const float* __restrict__ cond,
    const short* __restrict__ wp, short* __restrict__ hbt,
    const float* __restrict__ ib, const float* __restrict__ rbias,
    const float* __restrict__ sbias, const float* __restrict__ b1,
    const float* __restrict__ b2, float* __restrict__ outp,
    int* __restrict__ rdy, int* __restrict__ dn)
{
    __shared__ __align__(16) short sm[LDS_SHORTS];   // 108 KB

    const int tid  = threadIdx.x;
    const int lane = tid & 63;
    const int wv   = __builtin_amdgcn_readfirstlane(tid >> 6);   // 0..7
    const int wm   = wv & 3;            // 32-ch slice
    const int wt   = wv >> 2;           // 32-t slice
    const int lr   = lane & 15, lg = lane >> 4;
    const int bidx = blockIdx.x;
    const int b    = bidx / NTPB;
    const int ti   = bidx - b * NTPB;
    const int t0   = ti * 64;
    const int tc0  = wt * 32 + lr;
    const int tc1  = tc0 + 16;
    const int tg0  = t0 + tc0;
    const int tg1  = t0 + tc1;
    const int lane8 = lane * 8;
    const int awoff = wm * 1024 + lane8;
    const int chA  = wm * 32 + lg * 4;
    const int kbA  = wm * 4 + (lg >> 1);
    const int e0   = (lg & 1) * 4;

    short* const W0 = (short*)&sm[WBASE];
    short* const W1 = (short*)&sm[WBASE + 16384];

    // ---- stage input-conv weights (64 KB) + x tile (32 slots) + cond ----
    stage32(wp + IN_OFF, W0, wv, lane);
    stage32(wp + IN_OFF + 16384, W1, wv, lane);
    {
        const float* xb = x + (size_t)b * 256 * T_LEN + t0 + lane;
#pragma unroll
        for (int it = 0; it < 4; ++it) {
            int kb = wv * 4 + it;              // 0..31
            unsigned pk[4];
#pragma unroll
            for (int e = 0; e < 4; ++e)
                pk[e] = cvtpk(xb[(size_t)(kb * 8 + 2 * e) * T_LEN],
                              xb[(size_t)(kb * 8 + 2 * e + 1) * T_LEN]);
            *(uint4v*)&sm[(kb * 64 + lane) * 8] = *(uint4v*)pk;
        }
        if (wv < 6) {
            const float* cb = cond + (size_t)b * 80 * T_LEN + t0 + lane;
#pragma unroll
            for (int it = 0; it < 2; ++it) {
                int kb = wv * 2 + it;          // 0..11
                unsigned pk[4];
#pragma unroll
                for (int e = 0; e < 4; ++e) {
                    int c0 = kb * 8 + 2 * e, c1 = c0 + 1;
                    float v0 = (c0 < 80) ? cb[(size_t)c0 * T_LEN] : ((c0 == 80) ? 1.f : 0.f);
                    float v1 = (c1 < 80) ? cb[(size_t)c1 * T_LEN] : 0.f;
                    pk[e] = cvtpk(v0, v1);
                }
                *(uint4v*)&sm[R_CND + (kb * 64 + lane) * 8] = *(uint4v*)pk;
            }
        }
    }
    __syncthreads();

    // ---- input conv: h0 = Win @ x + ib ----
    f32x4 hres[2][2], skp[2][2];
    {
        f32x4 acc[2][2] = {{{0,0,0,0},{0,0,0,0}},{{0,0,0,0},{0,0,0,0}}};
        singleT2<4>(W0, sm, 0, 0, tc0, tc1, lg, awoff, acc);
        singleT2<4>(W1, sm, 0, 4, tc0, tc1, lg, awoff, acc);
        __syncthreads();   // all waves done reading x slots 0..31
#pragma unroll
        for (int mt = 0; mt < 2; ++mt) {
            int cb0 = chA + mt * 16;
            f32x4 bv = {ib[cb0], ib[cb0 + 1], ib[cb0 + 2], ib[cb0 + 3]};
            hres[mt][0] = acc[mt][0] + bv;
            hres[mt][1] = acc[mt][1] + bv;
            skp[mt][0] = (f32x4){0.f,0.f,0.f,0.f};
            skp[mt][1] = (f32x4){0.f,0.f,0.f,0.f};
        }
        short* hr0 = hbt + (size_t)b * SLAB + (size_t)(GUARD + tg0) * 128 + chA;
        short* hr1 = hbt + (size_t)b * SLAB + (size_t)(GUARD + tg1) * 128 + chA;
#pragma unroll
        for (int mt = 0; mt < 2; ++mt) {
            uint2v h0 = {cvtpk(hres[mt][0][0], hres[mt][0][1]), cvtpk(hres[mt][0][2], hres[mt][0][3])};
            uint2v h1 = {cvtpk(hres[mt][1][0], hres[mt][1][1]), cvtpk(hres[mt][1][2], hres[mt][1][3])};
            stg8_sc1(hr0 + mt * 16, h0);
            stg8_sc1(hr1 + mt * 16, h1);
            *(uint2v*)&sm[R_HT + ((kbA + mt * 2) * 64 + tc0) * 8 + e0] = h0;
            *(uint2v*)&sm[R_HT + ((kbA + mt * 2) * 64 + tc1) * 8 + e0] = h1;
        }
    }
    asm volatile("s_waitcnt vmcnt(0)" ::: "memory");
    __syncthreads();
    if (tid == 0) st_flag(&rdy[bidx], 1);

    // ---- 30 layers (R6 sync skeleton, dbuf-2 chunks) ----
    for (int li = 0; li < NLAYER; ++li) {
        const int d   = 1 << (li % 10);
        const int ksh = (d + 63) >> 6;
        const short* wl  = wp + (size_t)li * LS;
        const short* hcb = hbt + (size_t)((li & 3) * 2 + b) * SLAB;
        short*       hnb = hbt + (size_t)(((li + 1) & 3) * 2 + b) * SLAB;

        stage32(wl, W0, wv, lane);                                      // S0
        __syncthreads();                                                // barA
        if (lane == 0 && ti >= ksh) wait_ge(&rdy[bidx - ksh], li + 1);
        bf16x8 Bg[2][4];
        {
            const short* hr0 = hcb + (size_t)(GUARD + tg0 - d) * 128 + lg * 8;
            const short* hr1 = hcb + (size_t)(GUARD + tg1 - d) * 128 + lg * 8;
#pragma unroll
            for (int ks = 0; ks < 4; ++ks) {
                ldg16_sc1(&Bg[0][ks], hr0 + ks * 32);
                ldg16_sc1(&Bg[1][ks], hr1 + ks * 32);
            }
        }
        stage32(wl + C1, W1, wv, lane);                                 // S1
        f32x4 aa[2][2] = {{{0,0,0,0},{0,0,0,0}},{{0,0,0,0},{0,0,0,0}}};
        f32x4 ag[2][2] = {{{0,0,0,0},{0,0,0,0}},{{0,0,0,0},{0,0,0,0}}};
        pairT2<2>(W0, sm, R_HT, 0, tc0, tc1, lg, awoff, aa, ag);        // d1,g ks0-1
        __syncthreads();                                                // barB
        if (tid == 0) st_flag(&dn[bidx], li + 1);                       // Bg retired
        stage32(wl + C2, W0, wv, lane);                                 // S2
        pairT2<2>(W1, sm, R_HT, 2, tc0, tc1, lg, awoff, aa, ag);        // d1,g ks2-3
        __syncthreads();                                                // barC
        stage16(wl + C3, W1, wv, lane);                                 // S3 (16 KB)
        pairT2<2>(W0, sm, R_CND, 0, tc0, tc1, lg, awoff, aa, ag);       // c,cg ks0-1
        __syncthreads();                                                // barD
        stage32(wl + C4, W0, wv, lane);                                 // S4
        pairT2<1>(W1, sm, R_CND, 2, tc0, tc1, lg, awoff, aa, ag);       // c,cg ks2
        __syncthreads();                                                // barE
        stage32(wl + C5, W1, wv, lane);                                 // S5
        {   // d0 @ Bg (registers)
#pragma unroll
            for (int ks = 0; ks < 4; ++ks) {
#pragma unroll
                for (int mt = 0; mt < 2; ++mt) {
                    bf16x8 a = *(const bf16x8*)&W0[ks * 4096 + awoff + mt * 512];
                    aa[mt][0] = mfma_(a, Bg[0][ks], aa[mt][0]);
                    aa[mt][1] = mfma_(a, Bg[1][ks], aa[mt][1]);
                }
            }
        }
#pragma unroll
        for (int mt = 0; mt < 2; ++mt) {       // act -> R_OUT (both t-frags)
            uint2v o0 = {cvtpk(gated_act(aa[mt][0][0], ag[mt][0][0]),
                               gated_act(aa[mt][0][1], ag[mt][0][1])),
                         cvtpk(gated_act(aa[mt][0][2], ag[mt][0][2]),
                               gated_act(aa[mt][0][3], ag[mt][0][3]))};
            uint2v o1 = {cvtpk(gated_act(aa[mt][1][0], ag[mt][1][0]),
                               gated_act(aa[mt][1][1], ag[mt][1][1])),
                         cvtpk(gated_act(aa[mt][1][2], ag[mt][1][2]),
                               gated_act(aa[mt][1][3], ag[mt][1][3]))};
            *(uint2v*)&sm[R_OUT + ((kbA + mt * 2) * 64 + tc0) * 8 + e0] = o0;
            *(uint2v*)&sm[R_OUT + ((kbA + mt * 2) * 64 + tc1) * 8 + e0] = o1;
        }
        __syncthreads();                                                // barF
        stage32(wl + C6, W0, wv, lane);                                 // S6
        f32x4 ar[2][2]  = {{{0,0,0,0},{0,0,0,0}},{{0,0,0,0},{0,0,0,0}}};
        f32x4 as2[2][2] = {{{0,0,0,0},{0,0,0,0}},{{0,0,0,0},{0,0,0,0}}};
        pairT2<2>(W1, sm, R_OUT, 0, tc0, tc1, lg, awoff, ar, as2);      // r,s ks0-1
        __syncthreads();                                                // barG
        pairT2<2>(W0, sm, R_OUT, 2, tc0, tc1, lg, awoff, ar, as2);      // r,s ks2-3

        const float* rbl = rbias + li * 128 + chA;
        const float* sbl = sbias + li * 128 + chA;
#pragma unroll
        for (int mt = 0; mt < 2; ++mt) {
            f32x4 rbv = {rbl[mt*16], rbl[mt*16+1], rbl[mt*16+2], rbl[mt*16+3]};
            f32x4 sbv = {sbl[mt*16], sbl[mt*16+1], sbl[mt*16+2], sbl[mt*16+3]};
            hres[mt][0] = (hres[mt][0] + ar[mt][0] + rbv) * INV_SQRT2;
            hres[mt][1] = (hres[mt][1] + ar[mt][1] + rbv) * INV_SQRT2;
            skp[mt][0]  = skp[mt][0] + as2[mt][0] + sbv;
            skp[mt][1]  = skp[mt][1] + as2[mt][1] + sbv;
        }
        if (li < NLAYER - 1) {
            if (lane == 0 && li >= 3) {        // WAR vs readers of h^{li-3}
                int d3 = 1 << ((li - 3) % 10);
                int k3 = (d3 + 63) >> 6;
                if (ti + k3 < NTPB) wait_ge(&dn[bidx + k3], li - 2);
            }
            short* hr0 = hnb + (size_t)(GUARD + tg0) * 128 + chA;
            short* hr1 = hnb + (size_t)(GUARD + tg1) * 128 + chA;
#pragma unroll
            for (int mt = 0; mt < 2; ++mt) {
                uint2v h0 = {cvtpk(hres[mt][0][0], hres[mt][0][1]), cvtpk(hres[mt][0][2], hres[mt][0][3])};
                uint2v h1 = {cvtpk(hres[mt][1][0], hres[mt][1][1]), cvtpk(hres[mt][1][2], hres[mt][1][3])};
                stg8_sc1(hr0 + mt * 16, h0);
                stg8_sc1(hr1 + mt * 16, h1);
                *(uint2v*)&sm[R_HT + ((kbA + mt * 2) * 64 + tc0) * 8 + e0] = h0;
                *(uint2v*)&sm[R_HT + ((kbA + mt * 2) * 64 + tc1) * 8 + e0] = h1;
            }
        }
        __syncthreads();                                                // barH
        if (tid == 0 && li < NLAYER - 1) st_flag(&rdy[bidx], li + 2);
    }

    // ---- output head ----
#pragma unroll
    for (int mt = 0; mt < 2; ++mt) {           // skip -> R_HT (bf16)
        uint2v s0 = {cvtpk(skp[mt][0][0], skp[mt][0][1]), cvtpk(skp[mt][0][2], skp[mt][0][3])};
        uint2v s1 = {cvtpk(skp[mt][1][0], skp[mt][1][1]), cvtpk(skp[mt][1][2], skp[mt][1][3])};
        *(uint2v*)&sm[R_HT + ((kbA + mt * 2) * 64 + tc0) * 8 + e0] = s0;
        *(uint2v*)&sm[R_HT + ((kbA + mt * 2) * 64 + tc1) * 8 + e0] = s1;
    }
    stage32(wp + OUT1_OFF, W0, wv, lane);          // out1 (32 KB)  [R10 bug: was stage16]
    stage32(wp + OUT2_OFF, W1, wv, lane);          // out2 ks0-1 (32 KB)
    __syncthreads();
    f32x4 ay[2][2] = {{{0,0,0,0},{0,0,0,0}},{{0,0,0,0},{0,0,0,0}}};
    singleT2<4>(W0, sm, R_HT, 0, tc0, tc1, lg, awoff, ay);
    __syncthreads();                               // W0 reads done
    stage32(wp + OUT2_OFF + 16384, W0, wv, lane);  // out2 ks2-3 (32 KB)
#pragma unroll
    for (int mt = 0; mt < 2; ++mt) {               // y = relu(. + b1) -> R_OUT
        int cb0 = chA + mt * 16;
        f32x4 bv = {b1[cb0], b1[cb0+1], b1[cb0+2], b1[cb0+3]};
        f32x4 y0 = ay[mt][0] + bv, y1 = ay[mt][1] + bv;
        uint2v p0 = {cvtpk(fmaxf(y0[0],0.f), fmaxf(y0[1],0.f)),
                     cvtpk(fmaxf(y0[2],0.f), fmaxf(y0[3],0.f))};
        uint2v p1 = {cvtpk(fmaxf(y1[0],0.f), fmaxf(y1[1],0.f)),
                     cvtpk(fmaxf(y1[2],0.f), fmaxf(y1[3],0.f))};
        *(uint2v*)&sm[R_OUT + ((kbA + mt * 2) * 64 + tc0) * 8 + e0] = p0;
        *(uint2v*)&sm[R_OUT + ((kbA + mt * 2) * 64 + tc1) * 8 + e0] = p1;
    }
    __syncthreads();                               // out2b staged, y visible
    f32x4 ao[2][4] = {{{0,0,0,0},{0,0,0,0},{0,0,0,0},{0,0,0,0}},
                      {{0,0,0,0},{0,0,0,0},{0,0,0,0},{0,0,0,0}}};
#pragma unroll
    for (int ks = 0; ks < 4; ++ks) {
        const short* wch = (ks < 2) ? W1 : W0;
        int kk = ks & 1;
        bf16x8 Bf[4];
#pragma unroll
        for (int tf = 0; tf < 4; ++tf)
            Bf[tf] = *(const bf16x8*)&sm[R_OUT + (ks * 4 + lg) * 512 + (tf * 16 + lr) * 8];
#pragma unroll
        for (int mt = 0; mt < 2; ++mt) {
            bf16x8 A = *(const bf16x8*)&wch[((kk * 16) + wv * 2 + mt) * 512 + lane8];
#pragma unroll
            for (int tf = 0; tf < 4; ++tf)
                ao[mt][tf] = mfma_(A, Bf[tf], ao[mt][tf]);
        }
    }
#pragma unroll
    for (int mt = 0; mt < 2; ++mt) {
        int ch2 = (wv * 2 + mt) * 16 + lg * 4;
#pragma unroll
        for (int tf = 0; tf < 4; ++tf) {
            float* op = outp + ((size_t)(b * 256 + ch2)) * T_LEN + t0 + tf * 16 + lr;
            op[0]         = ao[mt][tf][0] + b2[ch2];
            op[T_LEN]     = ao[mt][tf][1] + b2[ch2 + 1];
            op[2 * T_LEN] = ao[mt][tf][2] + b2[ch2 + 2];
            op[3 * T_LEN] = ao[mt][tf][3] + b2[ch2 + 3];
        }
    }
}

extern "C" void kernel_launch(void* const* d_in, const int* in_sizes, int n_in,
                              void* d_out, int out_size, void* d_ws, size_t ws_size,
                              hipStream_t stream)
{
    const float* x       = (const float*)d_in[0];
    const float* cond    = (const float*)d_in[1];
    const float* input_w = (const float*)d_in[2];
    const float* input_b = (const float*)d_in[3];
    const float* dil_w   = (const float*)d_in[4];
    const float* dil_b   = (const float*)d_in[5];
    const float* gate_w  = (const float*)d_in[6];
    const float* gate_b  = (const float*)d_in[7];
    const float* cond_w  = (const float*)d_in[8];
    const float* cond_b  = (const float*)d_in[9];
    const float* condg_w = (const float*)d_in[10];
    const float* condg_b = (const float*)d_in[11];
    const float* res_w   = (const float*)d_in[12];
    const float* res_b   = (const float*)d_in[13];
    const float* skip_w  = (const float*)d_in[14];
    const float* skip_b  = (const float*)d_in[15];
    const float* out1_w  = (const float*)d_in[16];
    const float* out1_b  = (const float*)d_in[17];
    const float* out2_w  = (const float*)d_in[18];
    const float* out2_b  = (const float*)d_in[19];
    float* outp = (float*)d_out;

    short* wpk = (short*)d_ws;                         // 6400*512 shorts
    short* hbt = wpk + (size_t)6400 * 512;             // 8 slabs (4 levels x 2 batches)
    int*   flg = (int*)(hbt + (size_t)8 * SLAB);       // 512 ints
    int*   rdy = flg;
    int*   dn  = flg + 256;

    k_pack<<<1600, 256, 0, stream>>>(dil_w, gate_w, cond_w, condg_w, res_w, skip_w,
                                     input_w, out1_w, out2_w,
                                     dil_b, cond_b, gate_b, condg_b, wpk, hbt, flg);

    void* args[] = {(void*)&x, (void*)&cond, (void*)&wpk, (void*)&hbt,
                    (void*)&input_b, (void*)&res_b, (void*)&skip_b,
                    (void*)&out1_b, (void*)&out2_b, (void*)&outp,
                    (void*)&rdy, (void*)&dn};
    (void)hipLaunchCooperativeKernel((void*)k_wavenet, dim3(NBLK), dim3(512), args, 0, stream);
}